// Round 8
// baseline (545.118 us; speedup 1.0000x reference)
//
#include <hip/hip_runtime.h>

typedef __attribute__((ext_vector_type(4))) float f32x4;
typedef __attribute__((ext_vector_type(8))) short short8;
typedef __attribute__((ext_vector_type(4))) unsigned short u16x4;
typedef __attribute__((ext_vector_type(8))) unsigned short u16x8;

#define MFMA(a, b, c) __builtin_amdgcn_mfma_f32_16x16x32_bf16(a, b, c, 0, 0, 0)
#define GLOAD16(g, l) __builtin_amdgcn_global_load_lds( \
    (const __attribute__((address_space(1))) unsigned int*)(g), \
    (__attribute__((address_space(3))) unsigned int*)(l), 16, 0, 0)

__device__ inline unsigned short f2bf(float f) {
    unsigned int u = __float_as_uint(f);
    u += 0x7fffu + ((u >> 16) & 1u);   // RNE
    return (unsigned short)(u >> 16);
}

// ---------------------------------------------------------------------------
__global__ __launch_bounds__(256) void cvt_kernel(const float* __restrict__ in,
                                                  unsigned short* __restrict__ out, int n4,
                                                  float scale) {
    int i = blockIdx.x * 256 + threadIdx.x;
    if (i < n4) {
        f32x4 v = *(const f32x4*)(in + (long long)i * 4);
        u16x4 o;
#pragma unroll
        for (int j = 0; j < 4; j++) o[j] = f2bf(v[j] * scale);
        *(u16x4*)&out[(long long)i * 4] = o;
    }
}

// bias concat for fused QK: out[0:1024] = bq/32, out[1024:2048] = bk
__global__ __launch_bounds__(256) void biascat_kernel(const float* __restrict__ bq,
                                                      const float* __restrict__ bk,
                                                      float* __restrict__ out) {
    int i = blockIdx.x * 256 + threadIdx.x;
    if (i < 1024) out[i] = bq[i] * 0.03125f;
    else if (i < 2048) out[i] = bk[i - 1024];
}

// ---------------------------------------------------------------------------
__global__ __launch_bounds__(256) void ln_kernel(const float* __restrict__ x,
                                                 const float* __restrict__ g,
                                                 const float* __restrict__ be,
                                                 unsigned short* __restrict__ out) {
    const int row = blockIdx.x, tid = threadIdx.x;
    const float* px = x + (long long)row * 1024;
    f32x4 v = *(const f32x4*)(px + tid * 4);
    float s = v[0] + v[1] + v[2] + v[3];
    float q = v[0] * v[0] + v[1] * v[1] + v[2] * v[2] + v[3] * v[3];
#pragma unroll
    for (int o = 32; o; o >>= 1) { s += __shfl_xor(s, o); q += __shfl_xor(q, o); }
    __shared__ float sm[10];
    const int lane = tid & 63, wid = tid >> 6;
    if (lane == 0) { sm[wid] = s; sm[4 + wid] = q; }
    __syncthreads();
    if (tid == 0) {
        float ts = sm[0] + sm[1] + sm[2] + sm[3];
        float tq = sm[4] + sm[5] + sm[6] + sm[7];
        float mean = ts * (1.f / 1024.f);
        float var = tq * (1.f / 1024.f) - mean * mean;
        sm[8] = mean; sm[9] = rsqrtf(var + 1e-5f);
    }
    __syncthreads();
    float mean = sm[8], rs = sm[9];
    f32x4 gg = *(const f32x4*)(g + tid * 4);
    f32x4 bb = *(const f32x4*)(be + tid * 4);
    u16x4 o;
#pragma unroll
    for (int i = 0; i < 4; i++) o[i] = f2bf((v[i] - mean) * rs * gg[i] + bb[i]);
    *(u16x4*)&out[(long long)row * 1024 + tid * 4] = o;
}

// ---------------------------------------------------------------------------
// Causal softmax over row [0..t], writes bf16 probs IN-PLACE over the fp32 row.
__global__ __launch_bounds__(256) void softmax_kernel(float* __restrict__ S) {
    const int T = 2048;
    const int t = blockIdx.x, b = blockIdx.y, tid = threadIdx.x;
    float* row = S + ((long long)b * T + t) * T;
    const int base = tid * 8;
    f32x4 v0 = *(const f32x4*)(row + base);
    f32x4 v1 = *(const f32x4*)(row + base + 4);
    float mx = -1e30f;
#pragma unroll
    for (int i = 0; i < 4; i++) {
        if (base + i <= t)     mx = fmaxf(mx, v0[i]);
        if (base + 4 + i <= t) mx = fmaxf(mx, v1[i]);
    }
#pragma unroll
    for (int o = 32; o; o >>= 1) mx = fmaxf(mx, __shfl_xor(mx, o));
    __shared__ float sm[10];
    const int lane = tid & 63, wid = tid >> 6;
    if (lane == 0) sm[wid] = mx;
    __syncthreads();
    if (tid == 0) sm[8] = fmaxf(fmaxf(sm[0], sm[1]), fmaxf(sm[2], sm[3]));
    __syncthreads();
    float M = sm[8];
    float e[8]; float s = 0.f;
#pragma unroll
    for (int i = 0; i < 4; i++) {
        e[i]     = (base + i <= t)     ? __expf(v0[i] - M) : 0.f;
        e[4 + i] = (base + 4 + i <= t) ? __expf(v1[i] - M) : 0.f;
        s += e[i] + e[4 + i];
    }
#pragma unroll
    for (int o = 32; o; o >>= 1) s += __shfl_xor(s, o);
    if (lane == 0) sm[4 + wid] = s;
    __syncthreads();
    if (tid == 0) sm[9] = 1.f / (sm[4] + sm[5] + sm[6] + sm[7]);
    __syncthreads();
    float inv = sm[9];
    unsigned short* P = (unsigned short*)row;
    u16x8 o;
#pragma unroll
    for (int i = 0; i < 8; i++) o[i] = f2bf(e[i] * inv);
    *(u16x8*)&P[base] = o;
}

// ---------------------------------------------------------------------------
// m97-structure GEMM: Y[M,N] = A[M,K](bf16) @ B[N,K]^T(bf16) (+bias).
// 128x128 tile, BK=64, 256 threads (4 waves 2x2, 64x64/wave = 4x4 frags).
// SINGLE-buffered 32KB LDS -> ~3 blocks/CU; plain __syncthreads 2-barrier
// loop (cross-block wave overlap hides staging; m97 mechanism).
// Zero-conflict XOR swizzle: 16B chunk ^= (row&7), pre-applied to the global
// source (linear global_load_lds dest) and to the ds_read offsets.
// MODE: 0 fp32 | 1 fp32+residual | 2 bf16 (*scale) | 3 bf16 transposed
//       4 fp32 AND bf16 | 5 bf16 GELU
// flags: bit0 = causal block skip (n0>m0), bit1 = K limited to m0+128
template <int MODE>
__global__ __launch_bounds__(256) void gemm128(
    const unsigned short* __restrict__ A, int lda, long long sA,
    const unsigned short* __restrict__ Bw, int ldb, long long sB,
    const float* __restrict__ bias,
    const float* __restrict__ resid, long long sR,
    float* __restrict__ outf, unsigned short* __restrict__ outb,
    int ldo, long long sO, int K, float scale, int flags) {
    const int m0 = blockIdx.y * 128, n0 = blockIdx.x * 128;
    if ((flags & 1) && n0 > m0) return;
    const int bz = blockIdx.z;
    A += (long long)bz * sA; Bw += (long long)bz * sB;
    if (resid) resid += (long long)bz * sR;
    if (outf) outf += (long long)bz * sO;
    if (outb) outb += (long long)bz * sO;
    const int Keff = (flags & 2) ? (m0 + 128 < K ? m0 + 128 : K) : K;

    __shared__ __align__(16) unsigned short LDS[2 * 8192];   // A | B, 32 KB
    unsigned short* As = LDS;
    unsigned short* Bs = LDS + 8192;

    const int tid = threadIdx.x, lane = tid & 63, wid = tid >> 6;

    // staging map: 4 lines per matrix; line l covers 16B-chunks p = l*256+tid
    // row r = p>>3 (8 chunks per 64-col row); source chunk = (p&7) ^ (r&7)
    const unsigned short* srcA[4]; const unsigned short* srcB[4]; int dst[4];
#pragma unroll
    for (int l = 0; l < 4; l++) {
        int p = l * 256 + tid;
        int r = p >> 3, cs = (p & 7) ^ (r & 7);
        srcA[l] = A + (long long)(m0 + r) * lda + cs * 8;
        srcB[l] = Bw + (long long)(n0 + r) * ldb + cs * 8;
        dst[l] = l * 2048 + wid * 512;       // shorts; +lane*16B implicit
    }

    // fragment read offsets (swizzled), [row][64] shorts layout
    const int wm = (wid >> 1) * 64, wn = (wid & 1) * 64;
    const int fr = lane & 15, kq = lane >> 4;   // k-quarter 0..3
    int ao[4][2], bo[4][2];
#pragma unroll
    for (int i = 0; i < 4; i++) {
        int ra = wm + i * 16 + fr, rb = wn + i * 16 + fr;
#pragma unroll
        for (int s = 0; s < 2; s++) {
            ao[i][s] = ra * 64 + (((s * 4 + kq) ^ (ra & 7)) * 8);
            bo[i][s] = rb * 64 + (((s * 4 + kq) ^ (rb & 7)) * 8);
        }
    }

    f32x4 acc[4][4] = {};
    for (int k0 = 0; k0 < Keff; k0 += 64) {
#pragma unroll
        for (int l = 0; l < 4; l++) GLOAD16(srcA[l] + k0, As + dst[l]);
#pragma unroll
        for (int l = 0; l < 4; l++) GLOAD16(srcB[l] + k0, Bs + dst[l]);
        __syncthreads();
        {
            short8 a[4], b[4];
#pragma unroll
            for (int i = 0; i < 4; i++) { a[i] = *(const short8*)&As[ao[i][0]];
                                          b[i] = *(const short8*)&Bs[bo[i][0]]; }
#pragma unroll
            for (int i = 0; i < 4; i++)
#pragma unroll
                for (int j = 0; j < 4; j++)
                    acc[i][j] = MFMA(a[i], b[j], acc[i][j]);
#pragma unroll
            for (int i = 0; i < 4; i++) { a[i] = *(const short8*)&As[ao[i][1]];
                                          b[i] = *(const short8*)&Bs[bo[i][1]]; }
#pragma unroll
            for (int i = 0; i < 4; i++)
#pragma unroll
                for (int j = 0; j < 4; j++)
                    acc[i][j] = MFMA(a[i], b[j], acc[i][j]);
        }
        __syncthreads();
    }

    const int cc = lane & 15, rr = (lane >> 4) * 4;
#pragma unroll
    for (int fm = 0; fm < 4; fm++)
#pragma unroll
        for (int fn = 0; fn < 4; fn++) {
            f32x4 av = acc[fm][fn];
            int colg = n0 + wn + fn * 16 + cc;
            int rowg0 = m0 + wm + fm * 16 + rr;
            float bv = bias ? bias[colg] : 0.f;
            if (MODE == 3) {
                u16x4 o;
#pragma unroll
                for (int i = 0; i < 4; i++) o[i] = f2bf((av[i] + bv) * scale);
                *(u16x4*)&outb[(long long)colg * ldo + rowg0] = o;
            } else {
#pragma unroll
                for (int i = 0; i < 4; i++) {
                    float v = av[i] + bv;
                    long long idx = (long long)(rowg0 + i) * ldo + colg;
                    if (MODE == 0) outf[idx] = v;
                    if (MODE == 1) outf[idx] = v + resid[idx];
                    if (MODE == 2) outb[idx] = f2bf(v * scale);
                    if (MODE == 4) { outf[idx] = v; outb[idx] = f2bf(v); }
                    if (MODE == 5) outb[idx] = f2bf(0.5f * v * (1.f + erff(v * 0.70710678f)));
                }
            }
        }
}

// ---------------------------------------------------------------------------
extern "C" void kernel_launch(void* const* d_in, const int* in_sizes, int n_in,
                              void* d_out, int out_size, void* d_ws, size_t ws_size,
                              hipStream_t stream) {
    const float* x      = (const float*)d_in[0];
    const float* g1     = (const float*)d_in[1];
    const float* be1    = (const float*)d_in[2];
    const float* b_lin1 = (const float*)d_in[4];
    const float* bq     = (const float*)d_in[6];
    const float* bk     = (const float*)d_in[8];
    const float* bv     = (const float*)d_in[10];
    const float* b_lin2 = (const float*)d_in[12];
    const float* g2     = (const float*)d_in[13];
    const float* be2    = (const float*)d_in[14];
    const float* b_ff1  = (const float*)d_in[16];
    const float* b_ff2  = (const float*)d_in[18];

    const long long MB = 1024LL * 1024LL;
    char* ws = (char*)d_ws;
    unsigned short* xn1 = (unsigned short*)(ws + 0);        // 16MB, dead after lin1
    unsigned short* x1b = (unsigned short*)(ws + 16 * MB);  // 16MB, dead after QKV
    float*          S   = (float*)(ws + 0);                 // 64MB, scores->probs
    float*          bqk = (float*)(ws + 60 * MB);           // 8KB, dead after QK gemm
    float*          x1f = (float*)(ws + 64 * MB);           // 32MB, resid for lin2
    unsigned short* xn2 = (unsigned short*)(ws + 64 * MB);  // reuses x1f after LN2
    unsigned short* qk  = (unsigned short*)(ws + 96 * MB);  // 32MB [8192,2048] Q||K
    unsigned short* vT  = (unsigned short*)(ws + 128 * MB); // 16MB transposed V
    unsigned short* attn= (unsigned short*)(ws + 96 * MB);  // reuses qk after scores
    unsigned short* h   = (unsigned short*)(ws + 96 * MB);  // 32MB, after lin2
    float*          x2  = (float*)(ws + 144 * MB);          // 32MB
    unsigned short* wb1 = (unsigned short*)(ws + 176 * MB);
    unsigned short* wbq = (unsigned short*)(ws + 178 * MB); // wbq+wbk contiguous =
    unsigned short* wbk = (unsigned short*)(ws + 180 * MB); //   combined [2048,1024]
    unsigned short* wbv = (unsigned short*)(ws + 182 * MB);
    unsigned short* wb2 = (unsigned short*)(ws + 184 * MB);
    unsigned short* wbf1= (unsigned short*)(ws + 186 * MB); // 4MB
    unsigned short* wbf2= (unsigned short*)(ws + 190 * MB); // 4MB

    auto cvt = [&](const void* src, unsigned short* dst, long long n, float sc) {
        int n4 = (int)(n / 4);
        cvt_kernel<<<(n4 + 255) / 256, 256, 0, stream>>>((const float*)src, dst, n4, sc);
    };
    cvt(d_in[3], wb1, 1048576, 1.f);
    cvt(d_in[5], wbq, 1048576, 0.03125f);   // fold 1/sqrt(D) into Q weights
    cvt(d_in[7], wbk, 1048576, 1.f);
    cvt(d_in[9], wbv, 1048576, 1.f);
    cvt(d_in[11], wb2, 1048576, 1.f);
    cvt(d_in[15], wbf1, 2097152, 1.f);
    cvt(d_in[17], wbf2, 2097152, 1.f);
    biascat_kernel<<<8, 256, 0, stream>>>(bq, bk, bqk);

    // LN1
    ln_kernel<<<8192, 256, 0, stream>>>(x, g1, be1, xn1);
    // lin1: fp32 (residual base) + bf16
    gemm128<4><<<dim3(8, 64, 1), 256, 0, stream>>>(xn1, 1024, 0, wb1, 1024, 0, b_lin1,
        nullptr, 0, x1f, x1b, 1024, 0, 1024, 1.f, 0);
    // fused Q||K -> qk [8192, 2048] (Q pre-scaled by 1/32)
    gemm128<2><<<dim3(16, 64, 1), 256, 0, stream>>>(x1b, 1024, 0, wbq, 1024, 0, bqk,
        nullptr, 0, nullptr, qk, 2048, 0, 1024, 1.f, 0);
    // V, transposed per batch: vT[b][d][t]
    gemm128<3><<<dim3(8, 16, 4), 256, 0, stream>>>(x1b, 1024, 2048LL * 1024, wbv, 1024, 0, bv,
        nullptr, 0, nullptr, vT, 2048, 2097152LL, 1024, 1.f, 0);
    // scores (causal blocks only), fp32: A = Q cols, B = K cols of qk
    gemm128<0><<<dim3(16, 16, 4), 256, 0, stream>>>(qk, 2048, 4194304LL, qk + 1024, 2048, 4194304LL,
        nullptr, nullptr, 0, S, nullptr, 2048, 4194304LL, 1024, 1.f, 1);
    // softmax -> bf16 probs in place
    softmax_kernel<<<dim3(2048, 4), 256, 0, stream>>>(S);
    // PV: attn = P @ V  (A = bf16 probs with row stride 4096, B = vT), K-limit
    gemm128<2><<<dim3(8, 16, 4), 256, 0, stream>>>((unsigned short*)S, 4096, 8388608LL,
        vT, 2048, 2097152LL, nullptr, nullptr, 0, nullptr, attn, 1024, 2097152LL, 2048, 1.f, 2);
    // lin2 + residual(x1f) -> x2 fp32
    gemm128<1><<<dim3(8, 64, 1), 256, 0, stream>>>(attn, 1024, 0, wb2, 1024, 0, b_lin2,
        x1f, 0, x2, nullptr, 1024, 0, 1024, 1.f, 0);
    // LN2
    ln_kernel<<<8192, 256, 0, stream>>>(x2, g2, be2, xn2);
    // FFN1 + exact GELU -> h bf16 [8192,2048]
    gemm128<5><<<dim3(16, 64, 1), 256, 0, stream>>>(xn2, 1024, 0, wbf1, 1024, 0, b_ff1,
        nullptr, 0, nullptr, h, 2048, 0, 1024, 1.f, 0);
    // FFN2 + residual(x2) -> d_out fp32
    gemm128<1><<<dim3(8, 64, 1), 256, 0, stream>>>(h, 2048, 0, wbf2, 2048, 0, b_ff2,
        x2, 0, (float*)d_out, nullptr, 1024, 0, 2048, 1.f, 0);
}

// Round 10
// 483.178 us; speedup vs baseline: 1.1282x; 1.1282x over previous
//
#include <hip/hip_runtime.h>

typedef __attribute__((ext_vector_type(4))) float f32x4;
typedef __attribute__((ext_vector_type(8))) short short8;
typedef __attribute__((ext_vector_type(4))) unsigned short u16x4;
typedef __attribute__((ext_vector_type(8))) unsigned short u16x8;

#define MFMA(a, b, c) __builtin_amdgcn_mfma_f32_16x16x32_bf16(a, b, c, 0, 0, 0)
#define GLOAD16(g, l) __builtin_amdgcn_global_load_lds( \
    (const __attribute__((address_space(1))) unsigned int*)(g), \
    (__attribute__((address_space(3))) unsigned int*)(l), 16, 0, 0)
#define BARX() __builtin_amdgcn_s_barrier()
#define VM0 asm volatile("s_waitcnt vmcnt(0)" ::: "memory")

__device__ inline unsigned short f2bf(float f) {
    unsigned int u = __float_as_uint(f);
    u += 0x7fffu + ((u >> 16) & 1u);   // RNE
    return (unsigned short)(u >> 16);
}

// ---------------------------------------------------------------------------
__global__ __launch_bounds__(256) void cvt_kernel(const float* __restrict__ in,
                                                  unsigned short* __restrict__ out, int n4,
                                                  float scale) {
    int i = blockIdx.x * 256 + threadIdx.x;
    if (i < n4) {
        f32x4 v = *(const f32x4*)(in + (long long)i * 4);
        u16x4 o;
#pragma unroll
        for (int j = 0; j < 4; j++) o[j] = f2bf(v[j] * scale);
        *(u16x4*)&out[(long long)i * 4] = o;
    }
}

// bias concat for fused QK: out[0:1024] = bq/32, out[1024:2048] = bk
__global__ __launch_bounds__(256) void biascat_kernel(const float* __restrict__ bq,
                                                      const float* __restrict__ bk,
                                                      float* __restrict__ out) {
    int i = blockIdx.x * 256 + threadIdx.x;
    if (i < 1024) out[i] = bq[i] * 0.03125f;
    else if (i < 2048) out[i] = bk[i - 1024];
}

// ---------------------------------------------------------------------------
__global__ __launch_bounds__(256) void ln_kernel(const float* __restrict__ x,
                                                 const float* __restrict__ g,
                                                 const float* __restrict__ be,
                                                 unsigned short* __restrict__ out) {
    const int row = blockIdx.x, tid = threadIdx.x;
    const float* px = x + (long long)row * 1024;
    f32x4 v = *(const f32x4*)(px + tid * 4);
    float s = v[0] + v[1] + v[2] + v[3];
    float q = v[0] * v[0] + v[1] * v[1] + v[2] * v[2] + v[3] * v[3];
#pragma unroll
    for (int o = 32; o; o >>= 1) { s += __shfl_xor(s, o); q += __shfl_xor(q, o); }
    __shared__ float sm[10];
    const int lane = tid & 63, wid = tid >> 6;
    if (lane == 0) { sm[wid] = s; sm[4 + wid] = q; }
    __syncthreads();
    if (tid == 0) {
        float ts = sm[0] + sm[1] + sm[2] + sm[3];
        float tq = sm[4] + sm[5] + sm[6] + sm[7];
        float mean = ts * (1.f / 1024.f);
        float var = tq * (1.f / 1024.f) - mean * mean;
        sm[8] = mean; sm[9] = rsqrtf(var + 1e-5f);
    }
    __syncthreads();
    float mean = sm[8], rs = sm[9];
    f32x4 gg = *(const f32x4*)(g + tid * 4);
    f32x4 bb = *(const f32x4*)(be + tid * 4);
    u16x4 o;
#pragma unroll
    for (int i = 0; i < 4; i++) o[i] = f2bf((v[i] - mean) * rs * gg[i] + bb[i]);
    *(u16x4*)&out[(long long)row * 1024 + tid * 4] = o;
}

// ---------------------------------------------------------------------------
// Causal softmax over row [0..t], writes bf16 probs IN-PLACE over the fp32 row.
__global__ __launch_bounds__(256) void softmax_kernel(float* __restrict__ S) {
    const int T = 2048;
    const int t = blockIdx.x, b = blockIdx.y, tid = threadIdx.x;
    float* row = S + ((long long)b * T + t) * T;
    const int base = tid * 8;
    f32x4 v0 = *(const f32x4*)(row + base);
    f32x4 v1 = *(const f32x4*)(row + base + 4);
    float mx = -1e30f;
#pragma unroll
    for (int i = 0; i < 4; i++) {
        if (base + i <= t)     mx = fmaxf(mx, v0[i]);
        if (base + 4 + i <= t) mx = fmaxf(mx, v1[i]);
    }
#pragma unroll
    for (int o = 32; o; o >>= 1) mx = fmaxf(mx, __shfl_xor(mx, o));
    __shared__ float sm[10];
    const int lane = tid & 63, wid = tid >> 6;
    if (lane == 0) sm[wid] = mx;
    __syncthreads();
    if (tid == 0) sm[8] = fmaxf(fmaxf(sm[0], sm[1]), fmaxf(sm[2], sm[3]));
    __syncthreads();
    float M = sm[8];
    float e[8]; float s = 0.f;
#pragma unroll
    for (int i = 0; i < 4; i++) {
        e[i]     = (base + i <= t)     ? __expf(v0[i] - M) : 0.f;
        e[4 + i] = (base + 4 + i <= t) ? __expf(v1[i] - M) : 0.f;
        s += e[i] + e[4 + i];
    }
#pragma unroll
    for (int o = 32; o; o >>= 1) s += __shfl_xor(s, o);
    if (lane == 0) sm[4 + wid] = s;
    __syncthreads();
    if (tid == 0) sm[9] = 1.f / (sm[4] + sm[5] + sm[6] + sm[7]);
    __syncthreads();
    float inv = sm[9];
    unsigned short* P = (unsigned short*)row;
    u16x8 o;
#pragma unroll
    for (int i = 0; i < 8; i++) o[i] = f2bf(e[i] * inv);
    *(u16x8*)&P[base] = o;
}

// ---------------------------------------------------------------------------
// T3-minimal 2-phase GEMM: Y[M,N] = A[M,K](bf16) @ B[N,K]^T(bf16) (+bias).
// 128x128 tile, BK=64, 4 waves 2x2 (64x64/wave = 4x4 frags).
// DOUBLE-buffered 64KB LDS -> 2 blocks/CU. Per K-tile: {issue next tile's
// 8 global_load_lds -> ds_read+32 MFMA (compiler-scheduled) -> vmcnt(0) ->
// raw s_barrier}. Loads land under the whole tile's compute; only ONE
// barrier+wait per tile (no __syncthreads force-drain). Zero-conflict XOR
// swizzle: 16B chunk ^= (row&7) on pre-swizzled global source + ds_read offs.
// MODE: 0 fp32 | 1 fp32+residual | 2 bf16 (*scale) | 3 bf16 transposed
//       4 fp32 AND bf16 | 5 bf16 GELU
// flags: bit0 = causal block skip (n0>m0), bit1 = K limited to m0+128
template <int MODE>
__global__ __launch_bounds__(256, 2) void gemm128(
    const unsigned short* __restrict__ A, int lda, long long sA,
    const unsigned short* __restrict__ Bw, int ldb, long long sB,
    const float* __restrict__ bias,
    const float* __restrict__ resid, long long sR,
    float* __restrict__ outf, unsigned short* __restrict__ outb,
    int ldo, long long sO, int K, float scale, int flags) {
    const int m0 = blockIdx.y * 128, n0 = blockIdx.x * 128;
    if ((flags & 1) && n0 > m0) return;
    const int bz = blockIdx.z;
    A += (long long)bz * sA; Bw += (long long)bz * sB;
    if (resid) resid += (long long)bz * sR;
    if (outf) outf += (long long)bz * sO;
    if (outb) outb += (long long)bz * sO;
    const int Keff = (flags & 2) ? (m0 + 128 < K ? m0 + 128 : K) : K;
    const int nt = Keff >> 6;

    __shared__ __align__(16) unsigned short LDS[2 * 16384];   // 64 KB: 2 x (A|B)

    const int tid = threadIdx.x, lane = tid & 63, wid = tid >> 6;

    // staging map: 4 lines per matrix; line l covers 16B-chunks p = l*256+tid
    // row r = p>>3 (8 chunks per 64-col row); source chunk = (p&7) ^ (r&7)
    const unsigned short* srcA[4]; const unsigned short* srcB[4]; int dst[4];
#pragma unroll
    for (int l = 0; l < 4; l++) {
        int p = l * 256 + tid;
        int r = p >> 3, cs = (p & 7) ^ (r & 7);
        srcA[l] = A + (long long)(m0 + r) * lda + cs * 8;
        srcB[l] = Bw + (long long)(n0 + r) * ldb + cs * 8;
        dst[l] = l * 2048 + wid * 512;       // shorts; +lane*16B implicit
    }

    // fragment read offsets (swizzled); A region at buf+0, B at buf+8192
    const int wm = (wid >> 1) * 64, wn = (wid & 1) * 64;
    const int fr = lane & 15, kq = lane >> 4;   // k-quarter 0..3
    int ao[4][2], bo[4][2];
#pragma unroll
    for (int i = 0; i < 4; i++) {
        int ra = wm + i * 16 + fr, rb = wn + i * 16 + fr;
#pragma unroll
        for (int s = 0; s < 2; s++) {
            ao[i][s] = ra * 64 + (((s * 4 + kq) ^ (ra & 7)) * 8);
            bo[i][s] = 8192 + rb * 64 + (((s * 4 + kq) ^ (rb & 7)) * 8);
        }
    }

    f32x4 acc[4][4] = {};

    // prologue: tile 0 -> buffer 0
#pragma unroll
    for (int l = 0; l < 4; l++) GLOAD16(srcA[l], LDS + dst[l]);
#pragma unroll
    for (int l = 0; l < 4; l++) GLOAD16(srcB[l], LDS + 8192 + dst[l]);
    VM0; BARX();

    int c = 0;
    for (int t = 0; t < nt; ++t) {
        // issue next tile into the other buffer (freed by last barrier)
        if (t + 1 < nt) {
            const int kn = (t + 1) * 64;
            unsigned short* Lp = LDS + (c ^ 1) * 16384;
#pragma unroll
            for (int l = 0; l < 4; l++) GLOAD16(srcA[l] + kn, Lp + dst[l]);
#pragma unroll
            for (int l = 0; l < 4; l++) GLOAD16(srcB[l] + kn, Lp + 8192 + dst[l]);
        }
        const unsigned short* Lc = LDS + c * 16384;
        short8 a[4], b[4];
#pragma unroll
        for (int i = 0; i < 4; i++) { a[i] = *(const short8*)&Lc[ao[i][0]];
                                      b[i] = *(const short8*)&Lc[bo[i][0]]; }
#pragma unroll
        for (int i = 0; i < 4; i++)
#pragma unroll
            for (int j = 0; j < 4; j++)
                acc[i][j] = MFMA(a[i], b[j], acc[i][j]);
#pragma unroll
        for (int i = 0; i < 4; i++) { a[i] = *(const short8*)&Lc[ao[i][1]];
                                      b[i] = *(const short8*)&Lc[bo[i][1]]; }
#pragma unroll
        for (int i = 0; i < 4; i++)
#pragma unroll
            for (int j = 0; j < 4; j++)
                acc[i][j] = MFMA(a[i], b[j], acc[i][j]);
        VM0;    // next tile's loads had the whole compute to land
        BARX(); // all waves done reading buf[c] AND all staging landed
        c ^= 1;
    }

    const int cc = lane & 15, rr = (lane >> 4) * 4;
#pragma unroll
    for (int fm = 0; fm < 4; fm++)
#pragma unroll
        for (int fn = 0; fn < 4; fn++) {
            f32x4 av = acc[fm][fn];
            int colg = n0 + wn + fn * 16 + cc;
            int rowg0 = m0 + wm + fm * 16 + rr;
            float bv = bias ? bias[colg] : 0.f;
            if (MODE == 3) {
                u16x4 o;
#pragma unroll
                for (int i = 0; i < 4; i++) o[i] = f2bf((av[i] + bv) * scale);
                *(u16x4*)&outb[(long long)colg * ldo + rowg0] = o;
            } else {
#pragma unroll
                for (int i = 0; i < 4; i++) {
                    float v = av[i] + bv;
                    long long idx = (long long)(rowg0 + i) * ldo + colg;
                    if (MODE == 0) outf[idx] = v;
                    if (MODE == 1) outf[idx] = v + resid[idx];
                    if (MODE == 2) outb[idx] = f2bf(v * scale);
                    if (MODE == 4) { outf[idx] = v; outb[idx] = f2bf(v); }
                    if (MODE == 5) outb[idx] = f2bf(0.5f * v * (1.f + erff(v * 0.70710678f)));
                }
            }
        }
}

// ---------------------------------------------------------------------------
extern "C" void kernel_launch(void* const* d_in, const int* in_sizes, int n_in,
                              void* d_out, int out_size, void* d_ws, size_t ws_size,
                              hipStream_t stream) {
    const float* x      = (const float*)d_in[0];
    const float* g1     = (const float*)d_in[1];
    const float* be1    = (const float*)d_in[2];
    const float* b_lin1 = (const float*)d_in[4];
    const float* bq     = (const float*)d_in[6];
    const float* bk     = (const float*)d_in[8];
    const float* bv     = (const float*)d_in[10];
    const float* b_lin2 = (const float*)d_in[12];
    const float* g2     = (const float*)d_in[13];
    const float* be2    = (const float*)d_in[14];
    const float* b_ff1  = (const float*)d_in[16];
    const float* b_ff2  = (const float*)d_in[18];

    const long long MB = 1024LL * 1024LL;
    char* ws = (char*)d_ws;
    unsigned short* xn1 = (unsigned short*)(ws + 0);        // 16MB, dead after lin1
    unsigned short* x1b = (unsigned short*)(ws + 16 * MB);  // 16MB, dead after QKV
    float*          S   = (float*)(ws + 0);                 // 64MB, scores->probs
    float*          bqk = (float*)(ws + 60 * MB);           // 8KB, dead after QK gemm
    float*          x1f = (float*)(ws + 64 * MB);           // 32MB, resid for lin2
    unsigned short* xn2 = (unsigned short*)(ws + 64 * MB);  // reuses x1f after LN2
    unsigned short* qk  = (unsigned short*)(ws + 96 * MB);  // 32MB [8192,2048] Q||K
    unsigned short* vT  = (unsigned short*)(ws + 128 * MB); // 16MB transposed V
    unsigned short* attn= (unsigned short*)(ws + 96 * MB);  // reuses qk after scores
    unsigned short* h   = (unsigned short*)(ws + 96 * MB);  // 32MB, after lin2
    float*          x2  = (float*)(ws + 144 * MB);          // 32MB
    unsigned short* wb1 = (unsigned short*)(ws + 176 * MB);
    unsigned short* wbq = (unsigned short*)(ws + 178 * MB); // wbq+wbk contiguous =
    unsigned short* wbk = (unsigned short*)(ws + 180 * MB); //   combined [2048,1024]
    unsigned short* wbv = (unsigned short*)(ws + 182 * MB);
    unsigned short* wb2 = (unsigned short*)(ws + 184 * MB);
    unsigned short* wbf1= (unsigned short*)(ws + 186 * MB); // 4MB
    unsigned short* wbf2= (unsigned short*)(ws + 190 * MB); // 4MB

    auto cvt = [&](const void* src, unsigned short* dst, long long n, float sc) {
        int n4 = (int)(n / 4);
        cvt_kernel<<<(n4 + 255) / 256, 256, 0, stream>>>((const float*)src, dst, n4, sc);
    };
    cvt(d_in[3], wb1, 1048576, 1.f);
    cvt(d_in[5], wbq, 1048576, 0.03125f);   // fold 1/sqrt(D) into Q weights
    cvt(d_in[7], wbk, 1048576, 1.f);
    cvt(d_in[9], wbv, 1048576, 1.f);
    cvt(d_in[11], wb2, 1048576, 1.f);
    cvt(d_in[15], wbf1, 2097152, 1.f);
    cvt(d_in[17], wbf2, 2097152, 1.f);
    biascat_kernel<<<8, 256, 0, stream>>>(bq, bk, bqk);

    // LN1
    ln_kernel<<<8192, 256, 0, stream>>>(x, g1, be1, xn1);
    // lin1: fp32 (residual base) + bf16
    gemm128<4><<<dim3(8, 64, 1), 256, 0, stream>>>(xn1, 1024, 0, wb1, 1024, 0, b_lin1,
        nullptr, 0, x1f, x1b, 1024, 0, 1024, 1.f, 0);
    // fused Q||K -> qk [8192, 2048] (Q pre-scaled by 1/32)
    gemm128<2><<<dim3(16, 64, 1), 256, 0, stream>>>(x1b, 1024, 0, wbq, 1024, 0, bqk,
        nullptr, 0, nullptr, qk, 2048, 0, 1024, 1.f, 0);
    // V, transposed per batch: vT[b][d][t]
    gemm128<3><<<dim3(8, 16, 4), 256, 0, stream>>>(x1b, 1024, 2048LL * 1024, wbv, 1024, 0, bv,
        nullptr, 0, nullptr, vT, 2048, 2097152LL, 1024, 1.f, 0);
    // scores (causal blocks only), fp32: A = Q cols, B = K cols of qk
    gemm128<0><<<dim3(16, 16, 4), 256, 0, stream>>>(qk, 2048, 4194304LL, qk + 1024, 2048, 4194304LL,
        nullptr, nullptr, 0, S, nullptr, 2048, 4194304LL, 1024, 1.f, 1);
    // softmax -> bf16 probs in place
    softmax_kernel<<<dim3(2048, 4), 256, 0, stream>>>(S);
    // PV: attn = P @ V  (A = bf16 probs with row stride 4096, B = vT), K-limit
    gemm128<2><<<dim3(8, 16, 4), 256, 0, stream>>>((unsigned short*)S, 4096, 8388608LL,
        vT, 2048, 2097152LL, nullptr, nullptr, 0, nullptr, attn, 1024, 2097152LL, 2048, 1.f, 2);
    // lin2 + residual(x1f) -> x2 fp32
    gemm128<1><<<dim3(8, 64, 1), 256, 0, stream>>>(attn, 1024, 0, wb2, 1024, 0, b_lin2,
        x1f, 0, x2, nullptr, 1024, 0, 1024, 1.f, 0);
    // LN2
    ln_kernel<<<8192, 256, 0, stream>>>(x2, g2, be2, xn2);
    // FFN1 + exact GELU -> h bf16 [8192,2048]
    gemm128<5><<<dim3(16, 64, 1), 256, 0, stream>>>(xn2, 1024, 0, wbf1, 1024, 0, b_ff1,
        nullptr, 0, nullptr, h, 2048, 0, 1024, 1.f, 0);
    // FFN2 + residual(x2) -> d_out fp32
    gemm128<1><<<dim3(8, 64, 1), 256, 0, stream>>>(h, 2048, 0, wbf2, 2048, 0, b_ff2,
        x2, 0, (float*)d_out, nullptr, 1024, 0, 2048, 1.f, 0);
}